// Round 2
// baseline (240.213 us; speedup 1.0000x reference)
//
#include <hip/hip_runtime.h>
#include <hip/hip_bf16.h>

// Problem constants: B=4, S=1024, D=512, H=8, DH=64, L=S=1024
#define SB 4
#define SS 1024
#define SD 512
#define SH 8
#define SDH 64

typedef short bf16x8 __attribute__((ext_vector_type(8)));   // 8 bf16 in 4 VGPRs
typedef float f32x4 __attribute__((ext_vector_type(4)));

#define MFMA(a, b, c) __builtin_amdgcn_mfma_f32_16x16x32_bf16(a, b, c, 0, 0, 0)

__device__ __forceinline__ void load_lds16(const void* g, void* l) {
  __builtin_amdgcn_global_load_lds(
      (__attribute__((address_space(1))) void*)(const_cast<void*>(g)),
      (__attribute__((address_space(3))) void*)(l), 16, 0, 0);
}

__device__ __forceinline__ float bf16bits(short s) {
  return __uint_as_float(((unsigned int)(unsigned short)s) << 16);
}

// ---------------- fused convert fp32 -> bf16 for q,k,v ----------------
__global__ __launch_bounds__(256) void k_cvt3(const float2* __restrict__ q,
                                              const float2* __restrict__ k,
                                              const float2* __restrict__ v,
                                              __hip_bfloat162* __restrict__ oq,
                                              __hip_bfloat162* __restrict__ ok,
                                              __hip_bfloat162* __restrict__ ov, int n2) {
  int z = blockIdx.y;
  const float2* in = z == 0 ? q : z == 1 ? k : v;
  __hip_bfloat162* out = z == 0 ? oq : z == 1 ? ok : ov;
  int i = blockIdx.x * blockDim.x + threadIdx.x;
  int st = gridDim.x * blockDim.x;
  for (; i < n2; i += st) out[i] = __float22bfloat162_rn(in[i]);
}

// ---------------- transpose + convert (4 weights fused via z) ----------------
__global__ __launch_bounds__(256) void k_trw(const float* __restrict__ w0,
                                             const float* __restrict__ w1,
                                             const float* __restrict__ w2,
                                             const float* __restrict__ w3,
                                             __hip_bfloat16* __restrict__ o0,
                                             __hip_bfloat16* __restrict__ o1,
                                             __hip_bfloat16* __restrict__ o2,
                                             __hip_bfloat16* __restrict__ o3) {
  __shared__ float tile[32][33];
  int z = blockIdx.z;
  const float* ip = z == 0 ? w0 : z == 1 ? w1 : z == 2 ? w2 : w3;
  __hip_bfloat16* op = z == 0 ? o0 : z == 1 ? o1 : z == 2 ? o2 : o3;
  int c0 = blockIdx.x * 32, r0 = blockIdx.y * 32;
  int tx = threadIdx.x & 31, ty = threadIdx.x >> 5;
  for (int rr = ty; rr < 32; rr += 8) tile[rr][tx] = ip[(size_t)(r0 + rr) * SD + c0 + tx];
  __syncthreads();
  for (int cc = ty; cc < 32; cc += 8)
    op[(size_t)(c0 + cc) * SD + r0 + tx] = __float2bfloat16(tile[tx][cc]);
}

// rel_emb [H, DH, L] -> relT [H, L, DH]
__global__ __launch_bounds__(256) void k_trr(const float* __restrict__ in,
                                             __hip_bfloat16* __restrict__ out) {
  __shared__ float tile[32][33];
  int b = blockIdx.z;  // head
  int c0 = blockIdx.x * 32, r0 = blockIdx.y * 32;  // R=DH=64 rows, C=S=1024 cols
  const float* ip = in + (size_t)b * SDH * SS;
  __hip_bfloat16* op = out + (size_t)b * SDH * SS;
  int tx = threadIdx.x & 31, ty = threadIdx.x >> 5;
  for (int rr = ty; rr < 32; rr += 8) tile[rr][tx] = ip[(size_t)(r0 + rr) * SS + c0 + tx];
  __syncthreads();
  for (int cc = ty; cc < 32; cc += 8)
    op[(size_t)(c0 + cc) * SDH + r0 + tx] = __float2bfloat16(tile[tx][cc]);
}

// ---------------- GEMM core: C[4096,512] = A[4096,512] * Bt[512,512]^T, 128x64 tile ----
// mode 0: out bf16 [b,h,s,dh]; mode 1: out bf16 [b,h,dh,s]; mode 2: out fp32 [M,N]
__device__ __forceinline__ void gemm_core(const __hip_bfloat16* __restrict__ A,
                                          const __hip_bfloat16* __restrict__ Bt,
                                          void* __restrict__ Cout, int mode) {
  __shared__ __hip_bfloat16 As[128 * 64];
  __shared__ __hip_bfloat16 Bs[64 * 64];
  const int t = threadIdx.x, w = t >> 6, lane = t & 63;
  const int quad = lane >> 4, l16 = lane & 15;
  const int m0 = blockIdx.y * 128, n0 = blockIdx.x * 64;
  const int wm = (w >> 1) * 64, wn = (w & 1) * 32;
  f32x4 zero4 = {0.0f, 0.0f, 0.0f, 0.0f};
  f32x4 acc[4][2];
#pragma unroll
  for (int mi = 0; mi < 4; ++mi)
#pragma unroll
    for (int nj = 0; nj < 2; ++nj) acc[mi][nj] = zero4;

  for (int kt = 0; kt < SD; kt += 64) {
#pragma unroll
    for (int c = 0; c < 4; ++c) {
      int ofs = c * 256 + t;
      int row = ofs >> 3, col = (ofs & 7) ^ (row & 7);
      load_lds16(A + (size_t)(m0 + row) * SD + kt + col * 8,
                 (char*)As + (size_t)(c * 256 + w * 64) * 16);
    }
#pragma unroll
    for (int c = 0; c < 2; ++c) {
      int ofs = c * 256 + t;
      int row = ofs >> 3, col = (ofs & 7) ^ (row & 7);
      load_lds16(Bt + (size_t)(n0 + row) * SD + kt + col * 8,
                 (char*)Bs + (size_t)(c * 256 + w * 64) * 16);
    }
    __syncthreads();
    bf16x8 af[4][2], bfr[2][2];
#pragma unroll
    for (int mi = 0; mi < 4; ++mi) {
      int row = wm + mi * 16 + l16;
#pragma unroll
      for (int ks = 0; ks < 2; ++ks)
        af[mi][ks] = *(const bf16x8*)((const char*)As + row * 128 +
                                      ((ks * 4 + quad) ^ (row & 7)) * 16);
    }
#pragma unroll
    for (int nj = 0; nj < 2; ++nj) {
      int row = wn + nj * 16 + l16;
#pragma unroll
      for (int ks = 0; ks < 2; ++ks)
        bfr[nj][ks] = *(const bf16x8*)((const char*)Bs + row * 128 +
                                       ((ks * 4 + quad) ^ (row & 7)) * 16);
    }
#pragma unroll
    for (int mi = 0; mi < 4; ++mi)
#pragma unroll
      for (int nj = 0; nj < 2; ++nj) {
        acc[mi][nj] = MFMA(af[mi][0], bfr[nj][0], acc[mi][nj]);
        acc[mi][nj] = MFMA(af[mi][1], bfr[nj][1], acc[mi][nj]);
      }
    __syncthreads();
  }
#pragma unroll
  for (int mi = 0; mi < 4; ++mi)
#pragma unroll
    for (int nj = 0; nj < 2; ++nj)
#pragma unroll
      for (int r = 0; r < 4; ++r) {
        int m = m0 + wm + mi * 16 + quad * 4 + r;
        int n = n0 + wn + nj * 16 + l16;
        float v = acc[mi][nj][r];
        if (mode == 2) {
          ((float*)Cout)[(size_t)m * SD + n] = v;
        } else {
          int b = m >> 10, s = m & 1023, hh = n >> 6, dh = n & 63;
          __hip_bfloat16 bv = __float2bfloat16(v);
          if (mode == 0)
            ((__hip_bfloat16*)Cout)[((size_t)(b * SH + hh) * SS + s) * SDH + dh] = bv;
          else
            ((__hip_bfloat16*)Cout)[((size_t)(b * SH + hh) * SDH + dh) * SS + s] = bv;
        }
      }
}

__global__ __launch_bounds__(256) void k_gemm_qkv(
    const __hip_bfloat16* __restrict__ Xq, const __hip_bfloat16* __restrict__ Xk,
    const __hip_bfloat16* __restrict__ Xv, const __hip_bfloat16* __restrict__ Wqt,
    const __hip_bfloat16* __restrict__ Wkt, const __hip_bfloat16* __restrict__ Wvt,
    __hip_bfloat16* __restrict__ Qb, __hip_bfloat16* __restrict__ Kb,
    __hip_bfloat16* __restrict__ Vt) {
  int z = blockIdx.z;
  const __hip_bfloat16* A = z == 0 ? Xq : z == 1 ? Xk : Xv;
  const __hip_bfloat16* Bt = z == 0 ? Wqt : z == 1 ? Wkt : Wvt;
  void* C = z == 0 ? (void*)Qb : z == 1 ? (void*)Kb : (void*)Vt;
  gemm_core(A, Bt, C, z == 2 ? 1 : 0);
}

__global__ __launch_bounds__(256) void k_gemm_o(const __hip_bfloat16* __restrict__ CTX,
                                                const __hip_bfloat16* __restrict__ Wot,
                                                float* __restrict__ Out) {
  gemm_core(CTX, Wot, Out, 2);
}

// ---------------- skewed rel bias -> SREL in flash fragment order -------------------
// SREL packed lower-tri 64x64 tiles: tile (ti,tj), tj<=ti, idx = ti*(ti+1)/2 + tj.
// inner offset = (lane-major): ((row>>4)*64 + ((row>>2)&3)*16 + (col&15))*16 + (col>>4)*4 + (row&3)
__global__ __launch_bounds__(256) void k_srel(const __hip_bfloat16* __restrict__ Qb,
                                              const __hip_bfloat16* __restrict__ relT,
                                              __hip_bfloat16* __restrict__ SREL) {
  const int bh = blockIdx.z, h = bh & 7;
  const int i0 = blockIdx.y * 128, l0 = blockIdx.x * 128;
  if (i0 + l0 + 254 < 1023) return;  // entire tile has j<0
  __shared__ __hip_bfloat16 As[128 * 64];
  __shared__ __hip_bfloat16 Bs[128 * 64];
  const __hip_bfloat16* A = Qb + (size_t)bh * SS * SDH;
  const __hip_bfloat16* Bt = relT + (size_t)h * SS * SDH;
  const int t = threadIdx.x, w = t >> 6, lane = t & 63;
  const int quad = lane >> 4, l16 = lane & 15;
  const int wm = (w >> 1) * 64, wn = (w & 1) * 64;
#pragma unroll
  for (int c = 0; c < 4; ++c) {
    int ofs = c * 256 + t;
    int row = ofs >> 3, col = (ofs & 7) ^ (row & 7);
    load_lds16(A + (size_t)(i0 + row) * SDH + col * 8,
               (char*)As + (size_t)(c * 256 + w * 64) * 16);
    load_lds16(Bt + (size_t)(l0 + row) * SDH + col * 8,
               (char*)Bs + (size_t)(c * 256 + w * 64) * 16);
  }
  __syncthreads();
  f32x4 zero4 = {0.0f, 0.0f, 0.0f, 0.0f};
  f32x4 acc[4][4];
#pragma unroll
  for (int mi = 0; mi < 4; ++mi)
#pragma unroll
    for (int nj = 0; nj < 4; ++nj) acc[mi][nj] = zero4;
  bf16x8 af[4][2], bfr[4][2];
#pragma unroll
  for (int mi = 0; mi < 4; ++mi) {
    int row = wm + mi * 16 + l16;
#pragma unroll
    for (int ks = 0; ks < 2; ++ks)
      af[mi][ks] = *(const bf16x8*)((const char*)As + row * 128 +
                                    ((ks * 4 + quad) ^ (row & 7)) * 16);
  }
#pragma unroll
  for (int nj = 0; nj < 4; ++nj) {
    int row = wn + nj * 16 + l16;
#pragma unroll
    for (int ks = 0; ks < 2; ++ks)
      bfr[nj][ks] = *(const bf16x8*)((const char*)Bs + row * 128 +
                                     ((ks * 4 + quad) ^ (row & 7)) * 16);
  }
#pragma unroll
  for (int mi = 0; mi < 4; ++mi)
#pragma unroll
    for (int nj = 0; nj < 4; ++nj) {
      acc[mi][nj] = MFMA(af[mi][0], bfr[nj][0], acc[mi][nj]);
      acc[mi][nj] = MFMA(af[mi][1], bfr[nj][1], acc[mi][nj]);
    }
#pragma unroll
  for (int mi = 0; mi < 4; ++mi)
#pragma unroll
    for (int nj = 0; nj < 4; ++nj)
#pragma unroll
      for (int r = 0; r < 4; ++r) {
        int i = i0 + wm + mi * 16 + quad * 4 + r;
        int l = l0 + wn + nj * 16 + l16;
        int j = l - 1023 + i;
        if (j >= 0) {
          int ti = i >> 6, tj = j >> 6, row = i & 63, col = j & 63;
          int inner = ((row >> 4) * 64 + ((row >> 2) & 3) * 16 + (col & 15)) * 16 +
                      (col >> 4) * 4 + (row & 3);
          SREL[((size_t)bh * 136 + ((ti * (ti + 1)) >> 1) + tj) * 4096 + inner] =
              __float2bfloat16(acc[mi][nj][r]);
        }
      }
}

// ---------------- split-j flash: static-shift softmax, partial (O,l) ----------------
__device__ const int TTm[40] = {0,1,2,3,4,4,5,5,6,6,7,7,8,8,8,9,9,9,10,10,10,11,11,11,
                                12,12,12,12,13,13,13,13,14,14,14,14,15,15,15,15};
__device__ const int CCm[40] = {0,0,0,0,0,1,0,1,0,1,0,1,0,1,2,0,1,2,0,1,2,0,1,2,
                                0,1,2,3,0,1,2,3,0,1,2,3,0,1,2,3};

__global__ __launch_bounds__(256) void k_flash(const __hip_bfloat16* __restrict__ Qb,
                                               const __hip_bfloat16* __restrict__ Kb,
                                               const __hip_bfloat16* __restrict__ Vt,
                                               const __hip_bfloat16* __restrict__ SREL,
                                               float* __restrict__ Opart,
                                               float* __restrict__ lpart) {
  __shared__ __hip_bfloat16 Klds[64 * 64];
  __shared__ __hip_bfloat16 Vlds[64 * 64];
  __shared__ __hip_bfloat16 Pbuf[64 * 72];
  const int t = threadIdx.x, w = t >> 6, lane = t & 63;
  const int quad = lane >> 4, l16 = lane & 15;
  const int idx = blockIdx.x, bh = blockIdx.y;
  const int tI = TTm[idx], c = CCm[idx];
  const int i0 = tI * 64;
  const int rem = tI + 1 - c * 4;
  const int nt = rem < 4 ? rem : 4;
  const size_t qbase = (size_t)bh * SS * SDH;

  const int qrow = i0 + w * 16 + l16;
  bf16x8 qf0 = *(const bf16x8*)(Qb + qbase + (size_t)qrow * SDH + quad * 8);
  bf16x8 qf1 = *(const bf16x8*)(Qb + qbase + (size_t)qrow * SDH + 32 + quad * 8);

  f32x4 zero4 = {0.0f, 0.0f, 0.0f, 0.0f};
  f32x4 acc_o[4];
#pragma unroll
  for (int dt = 0; dt < 4; ++dt) acc_o[dt] = zero4;
  float ls[4] = {0.0f, 0.0f, 0.0f, 0.0f};
  const int irow_base = i0 + w * 16 + quad * 4;
  const size_t sbase = ((size_t)bh * 136 + ((tI * (tI + 1)) >> 1)) * 4096 +
                       (size_t)(w * 64 + lane) * 16;

  for (int jt = 0; jt < nt; ++jt) {
    const int jtile = c * 4 + jt, j0 = jtile * 64;
#pragma unroll
    for (int cc = 0; cc < 2; ++cc) {
      int ofs = cc * 256 + t;
      int row = ofs >> 3, col = (ofs & 7) ^ (row & 7);
      load_lds16(Kb + qbase + (size_t)(j0 + row) * SDH + col * 8,
                 (char*)Klds + (size_t)(cc * 256 + w * 64) * 16);
      load_lds16(Vt + (size_t)bh * SDH * SS + (size_t)row * SS + j0 + col * 8,
                 (char*)Vlds + (size_t)(cc * 256 + w * 64) * 16);
    }
    // SREL bias: two coalesced 16B loads in exact lane order
    const __hip_bfloat16* sp = SREL + sbase + (size_t)jtile * 4096;
    bf16x8 sv0 = *(const bf16x8*)(sp);
    bf16x8 sv1 = *(const bf16x8*)(sp + 8);
    __syncthreads();

    f32x4 s[4];
#pragma unroll
    for (int nj = 0; nj < 4; ++nj) {
      int row = nj * 16 + l16;
      bf16x8 b0 = *(const bf16x8*)((const char*)Klds + row * 128 + (quad ^ (row & 7)) * 16);
      bf16x8 b1 = *(const bf16x8*)((const char*)Klds + row * 128 + ((4 + quad) ^ (row & 7)) * 16);
      f32x4 z = zero4;
      z = MFMA(qf0, b0, z);
      z = MFMA(qf1, b1, z);
      s[nj] = z;
    }
    // p = exp((qk + bias)*0.125 - 8); causal zero; accumulate per-lane row sums
#pragma unroll
    for (int nj = 0; nj < 4; ++nj) {
      int jcol = j0 + nj * 16 + l16;
#pragma unroll
      for (int r = 0; r < 4; ++r) {
        int irow = irow_base + r;
        short sb = (nj < 2) ? sv0[(nj & 1) * 4 + r] : sv1[(nj & 1) * 4 + r];
        float val = (s[nj][r] + bf16bits(sb)) * 0.125f - 8.0f;
        float p = (jcol <= irow) ? __expf(val) : 0.0f;
        s[nj][r] = p;
        ls[r] += p;
      }
    }
#pragma unroll
    for (int nj = 0; nj < 4; ++nj)
#pragma unroll
      for (int r = 0; r < 4; ++r)
        Pbuf[(w * 16 + quad * 4 + r) * 72 + nj * 16 + l16] = __float2bfloat16(s[nj][r]);
    __syncthreads();
#pragma unroll
    for (int js = 0; js < 2; ++js) {
      bf16x8 pa = *(const bf16x8*)(Pbuf + (size_t)(w * 16 + l16) * 72 + js * 32 + quad * 8);
#pragma unroll
      for (int dt = 0; dt < 4; ++dt) {
        int row = dt * 16 + l16;
        bf16x8 vb = *(const bf16x8*)((const char*)Vlds + row * 128 +
                                     ((js * 4 + quad) ^ (row & 7)) * 16);
        acc_o[dt] = MFMA(pa, vb, acc_o[dt]);
      }
    }
    __syncthreads();
  }
  // epilogue: reduce row sums across the 16-lane group, write partial O and l
  const size_t pbase = (size_t)(bh * 16 + tI) * 4 + c;
  float* Op = Opart + pbase * 4096;
#pragma unroll
  for (int r = 0; r < 4; ++r) {
    float sum = ls[r];
    sum += __shfl_xor(sum, 1, 64);
    sum += __shfl_xor(sum, 2, 64);
    sum += __shfl_xor(sum, 4, 64);
    sum += __shfl_xor(sum, 8, 64);
    int row = w * 16 + quad * 4 + r;
#pragma unroll
    for (int dt = 0; dt < 4; ++dt) Op[row * 64 + dt * 16 + l16] = acc_o[dt][r];
    if (l16 == 0) lpart[pbase * 64 + row] = sum;
  }
}

// ---------------- combine partials, normalize, write CTX bf16 ----------------
__global__ __launch_bounds__(256) void k_reduce(const float* __restrict__ Opart,
                                                const float* __restrict__ lpart,
                                                __hip_bfloat16* __restrict__ CTX) {
  const int tI = blockIdx.x, bh = blockIdx.y, b = bh >> 3, h = bh & 7;
  const int nc = tI / 4 + 1;
  const int tid = threadIdx.x;
  __shared__ float lsum[64];
  const size_t base = (size_t)(bh * 16 + tI) * 4;
  if (tid < 64) {
    float s = 0.0f;
    for (int cc = 0; cc < nc; ++cc) s += lpart[(base + cc) * 64 + tid];
    lsum[tid] = s;
  }
  __syncthreads();
  const int e0 = tid * 16;
  const int row = e0 >> 6, d0 = e0 & 63;
  float4 o[4] = {};
  for (int cc = 0; cc < nc; ++cc) {
    const float4* p = (const float4*)(Opart + (base + cc) * 4096);
#pragma unroll
    for (int vv = 0; vv < 4; ++vv) {
      float4 x = p[tid * 4 + vv];
      o[vv].x += x.x; o[vv].y += x.y; o[vv].z += x.z; o[vv].w += x.w;
    }
  }
  const float rl = 1.0f / lsum[row];
  __hip_bfloat16* op = CTX + ((size_t)b * SS + tI * 64 + row) * SD + h * SDH + d0;
#pragma unroll
  for (int vv = 0; vv < 4; ++vv) {
    op[vv * 4 + 0] = __float2bfloat16(o[vv].x * rl);
    op[vv * 4 + 1] = __float2bfloat16(o[vv].y * rl);
    op[vv * 4 + 2] = __float2bfloat16(o[vv].z * rl);
    op[vv * 4 + 3] = __float2bfloat16(o[vv].w * rl);
  }
}

extern "C" void kernel_launch(void* const* d_in, const int* in_sizes, int n_in,
                              void* d_out, int out_size, void* d_ws, size_t ws_size,
                              hipStream_t stream) {
  const float* queries = (const float*)d_in[0];
  const float* keys    = (const float*)d_in[1];
  const float* values  = (const float*)d_in[2];
  const float* Wq = (const float*)d_in[4];
  const float* Wk = (const float*)d_in[5];
  const float* Wv = (const float*)d_in[6];
  const float* Wo = (const float*)d_in[7];
  const float* rel = (const float*)d_in[8];

  char* ws = (char*)d_ws;
  size_t off = 0;
  auto alloc = [&](size_t bytes) {
    char* p = ws + off;
    off += (bytes + 255) & ~(size_t)255;
    return p;
  };
  const size_t XB = (size_t)SB * SS * SD * 2;   // 4 MiB
  const size_t WB = (size_t)SD * SD * 2;        // 512 KiB
  // persistent region
  __hip_bfloat16* Wqt  = (__hip_bfloat16*)alloc(WB);
  __hip_bfloat16* Wkt  = (__hip_bfloat16*)alloc(WB);
  __hip_bfloat16* Wvt  = (__hip_bfloat16*)alloc(WB);
  __hip_bfloat16* Wot  = (__hip_bfloat16*)alloc(WB);
  __hip_bfloat16* relT = (__hip_bfloat16*)alloc((size_t)SH * SS * SDH * 2);
  __hip_bfloat16* Qb   = (__hip_bfloat16*)alloc(XB);
  __hip_bfloat16* Kb   = (__hip_bfloat16*)alloc(XB);
  __hip_bfloat16* Vt   = (__hip_bfloat16*)alloc(XB);
  __hip_bfloat16* CTX  = (__hip_bfloat16*)alloc(XB);
  // union region: Xq/Xk/Xv (12 MiB, dead after qkv gemm) aliased by Opart/lpart
  char* uni = alloc((size_t)2048 * 4096 * 4 + (size_t)2048 * 64 * 4);  // 32.5 MiB
  __hip_bfloat16* Xq = (__hip_bfloat16*)uni;
  __hip_bfloat16* Xk = (__hip_bfloat16*)(uni + XB);
  __hip_bfloat16* Xv = (__hip_bfloat16*)(uni + 2 * XB);
  float* Opart = (float*)uni;
  float* lpart = (float*)(uni + (size_t)2048 * 4096 * 4);
  // SREL packed lower-tri tiles: 32 bh * 136 tiles * 8 KiB = 34 MiB
  __hip_bfloat16* SREL = (__hip_bfloat16*)alloc((size_t)SB * SH * 136 * 4096 * 2);
  if (off > ws_size) return;

  const int n2 = SB * SS * SD / 2;
  k_cvt3<<<dim3(512, 3), dim3(256), 0, stream>>>((const float2*)queries, (const float2*)keys,
                                                 (const float2*)values, (__hip_bfloat162*)Xq,
                                                 (__hip_bfloat162*)Xk, (__hip_bfloat162*)Xv, n2);
  k_trw<<<dim3(16, 16, 4), dim3(256), 0, stream>>>(Wq, Wk, Wv, Wo, Wqt, Wkt, Wvt, Wot);
  k_trr<<<dim3(SS / 32, SDH / 32, SH), dim3(256), 0, stream>>>(rel, relT);

  k_gemm_qkv<<<dim3(SD / 64, SB * SS / 128, 3), dim3(256), 0, stream>>>(
      Xq, Xk, Xv, Wqt, Wkt, Wvt, Qb, Kb, Vt);
  k_srel<<<dim3(SS / 128, SS / 128, SB * SH), dim3(256), 0, stream>>>(Qb, relT, SREL);
  k_flash<<<dim3(40, SB * SH), dim3(256), 0, stream>>>(Qb, Kb, Vt, SREL, Opart, lpart);
  k_reduce<<<dim3(16, SB * SH), dim3(256), 0, stream>>>(Opart, lpart, CTX);
  k_gemm_o<<<dim3(SD / 64, SB * SS / 128), dim3(256), 0, stream>>>(CTX, Wot, (float*)d_out);
}

// Round 3
// 168.472 us; speedup vs baseline: 1.4258x; 1.4258x over previous
//
#include <hip/hip_runtime.h>
#include <hip/hip_bf16.h>

// Problem constants: B=4, S=1024, D=512, H=8, DH=64, L=S=1024
#define SB 4
#define SS 1024
#define SD 512
#define SH 8
#define SDH 64

typedef short bf16x8 __attribute__((ext_vector_type(8)));   // 8 bf16 in 4 VGPRs
typedef float f32x4 __attribute__((ext_vector_type(4)));

#define MFMA(a, b, c) __builtin_amdgcn_mfma_f32_16x16x32_bf16(a, b, c, 0, 0, 0)

__device__ __forceinline__ void load_lds16(const void* g, void* l) {
  __builtin_amdgcn_global_load_lds(
      (__attribute__((address_space(1))) void*)(const_cast<void*>(g)),
      (__attribute__((address_space(3))) void*)(l), 16, 0, 0);
}

__device__ __forceinline__ float bf16bits(short s) {
  return __uint_as_float(((unsigned int)(unsigned short)s) << 16);
}

// ---------------- fused convert fp32 -> bf16 for q,k,v ----------------
__global__ __launch_bounds__(256) void k_cvt3(const float2* __restrict__ q,
                                              const float2* __restrict__ k,
                                              const float2* __restrict__ v,
                                              __hip_bfloat162* __restrict__ oq,
                                              __hip_bfloat162* __restrict__ ok,
                                              __hip_bfloat162* __restrict__ ov, int n2) {
  int z = blockIdx.y;
  const float2* in = z == 0 ? q : z == 1 ? k : v;
  __hip_bfloat162* out = z == 0 ? oq : z == 1 ? ok : ov;
  int i = blockIdx.x * blockDim.x + threadIdx.x;
  int st = gridDim.x * blockDim.x;
  for (; i < n2; i += st) out[i] = __float22bfloat162_rn(in[i]);
}

// ---------------- transpose + convert (4 weights fused via z) ----------------
__global__ __launch_bounds__(256) void k_trw(const float* __restrict__ w0,
                                             const float* __restrict__ w1,
                                             const float* __restrict__ w2,
                                             const float* __restrict__ w3,
                                             __hip_bfloat16* __restrict__ o0,
                                             __hip_bfloat16* __restrict__ o1,
                                             __hip_bfloat16* __restrict__ o2,
                                             __hip_bfloat16* __restrict__ o3) {
  __shared__ float tile[32][33];
  int z = blockIdx.z;
  const float* ip = z == 0 ? w0 : z == 1 ? w1 : z == 2 ? w2 : w3;
  __hip_bfloat16* op = z == 0 ? o0 : z == 1 ? o1 : z == 2 ? o2 : o3;
  int c0 = blockIdx.x * 32, r0 = blockIdx.y * 32;
  int tx = threadIdx.x & 31, ty = threadIdx.x >> 5;
  for (int rr = ty; rr < 32; rr += 8) tile[rr][tx] = ip[(size_t)(r0 + rr) * SD + c0 + tx];
  __syncthreads();
  for (int cc = ty; cc < 32; cc += 8)
    op[(size_t)(c0 + cc) * SD + r0 + tx] = __float2bfloat16(tile[tx][cc]);
}

// rel_emb [H, DH, L] -> relT [H, L, DH]
__global__ __launch_bounds__(256) void k_trr(const float* __restrict__ in,
                                             __hip_bfloat16* __restrict__ out) {
  __shared__ float tile[32][33];
  int b = blockIdx.z;  // head
  int c0 = blockIdx.x * 32, r0 = blockIdx.y * 32;
  const float* ip = in + (size_t)b * SDH * SS;
  __hip_bfloat16* op = out + (size_t)b * SDH * SS;
  int tx = threadIdx.x & 31, ty = threadIdx.x >> 5;
  for (int rr = ty; rr < 32; rr += 8) tile[rr][tx] = ip[(size_t)(r0 + rr) * SS + c0 + tx];
  __syncthreads();
  for (int cc = ty; cc < 32; cc += 8)
    op[(size_t)(c0 + cc) * SDH + r0 + tx] = __float2bfloat16(tile[tx][cc]);
}

// ---------------- GEMM core: C[4096,512] = A[4096,512] * Bt[512,512]^T, 128x64 tile ----
__device__ __forceinline__ void gemm_core(const __hip_bfloat16* __restrict__ A,
                                          const __hip_bfloat16* __restrict__ Bt,
                                          void* __restrict__ Cout, int mode) {
  __shared__ __hip_bfloat16 As[128 * 64];
  __shared__ __hip_bfloat16 Bs[64 * 64];
  const int t = threadIdx.x, w = t >> 6, lane = t & 63;
  const int quad = lane >> 4, l16 = lane & 15;
  const int m0 = blockIdx.y * 128, n0 = blockIdx.x * 64;
  const int wm = (w >> 1) * 64, wn = (w & 1) * 32;
  f32x4 zero4 = {0.0f, 0.0f, 0.0f, 0.0f};
  f32x4 acc[4][2];
#pragma unroll
  for (int mi = 0; mi < 4; ++mi)
#pragma unroll
    for (int nj = 0; nj < 2; ++nj) acc[mi][nj] = zero4;

  for (int kt = 0; kt < SD; kt += 64) {
#pragma unroll
    for (int c = 0; c < 4; ++c) {
      int ofs = c * 256 + t;
      int row = ofs >> 3, col = (ofs & 7) ^ (row & 7);
      load_lds16(A + (size_t)(m0 + row) * SD + kt + col * 8,
                 (char*)As + (size_t)(c * 256 + w * 64) * 16);
    }
#pragma unroll
    for (int c = 0; c < 2; ++c) {
      int ofs = c * 256 + t;
      int row = ofs >> 3, col = (ofs & 7) ^ (row & 7);
      load_lds16(Bt + (size_t)(n0 + row) * SD + kt + col * 8,
                 (char*)Bs + (size_t)(c * 256 + w * 64) * 16);
    }
    __syncthreads();
    bf16x8 af[4][2], bfr[2][2];
#pragma unroll
    for (int mi = 0; mi < 4; ++mi) {
      int row = wm + mi * 16 + l16;
#pragma unroll
      for (int ks = 0; ks < 2; ++ks)
        af[mi][ks] = *(const bf16x8*)((const char*)As + row * 128 +
                                      ((ks * 4 + quad) ^ (row & 7)) * 16);
    }
#pragma unroll
    for (int nj = 0; nj < 2; ++nj) {
      int row = wn + nj * 16 + l16;
#pragma unroll
      for (int ks = 0; ks < 2; ++ks)
        bfr[nj][ks] = *(const bf16x8*)((const char*)Bs + row * 128 +
                                       ((ks * 4 + quad) ^ (row & 7)) * 16);
    }
#pragma unroll
    for (int mi = 0; mi < 4; ++mi)
#pragma unroll
      for (int nj = 0; nj < 2; ++nj) {
        acc[mi][nj] = MFMA(af[mi][0], bfr[nj][0], acc[mi][nj]);
        acc[mi][nj] = MFMA(af[mi][1], bfr[nj][1], acc[mi][nj]);
      }
    __syncthreads();
  }
#pragma unroll
  for (int mi = 0; mi < 4; ++mi)
#pragma unroll
    for (int nj = 0; nj < 2; ++nj)
#pragma unroll
      for (int r = 0; r < 4; ++r) {
        int m = m0 + wm + mi * 16 + quad * 4 + r;
        int n = n0 + wn + nj * 16 + l16;
        float v = acc[mi][nj][r];
        if (mode == 2) {
          ((float*)Cout)[(size_t)m * SD + n] = v;
        } else {
          int b = m >> 10, s = m & 1023, hh = n >> 6, dh = n & 63;
          __hip_bfloat16 bv = __float2bfloat16(v);
          if (mode == 0)
            ((__hip_bfloat16*)Cout)[((size_t)(b * SH + hh) * SS + s) * SDH + dh] = bv;
          else
            ((__hip_bfloat16*)Cout)[((size_t)(b * SH + hh) * SDH + dh) * SS + s] = bv;
        }
      }
}

__global__ __launch_bounds__(256) void k_gemm_qkv(
    const __hip_bfloat16* __restrict__ Xq, const __hip_bfloat16* __restrict__ Xk,
    const __hip_bfloat16* __restrict__ Xv, const __hip_bfloat16* __restrict__ Wqt,
    const __hip_bfloat16* __restrict__ Wkt, const __hip_bfloat16* __restrict__ Wvt,
    __hip_bfloat16* __restrict__ Qb, __hip_bfloat16* __restrict__ Kb,
    __hip_bfloat16* __restrict__ Vt) {
  int z = blockIdx.z;
  const __hip_bfloat16* A = z == 0 ? Xq : z == 1 ? Xk : Xv;
  const __hip_bfloat16* Bt = z == 0 ? Wqt : z == 1 ? Wkt : Wvt;
  void* C = z == 0 ? (void*)Qb : z == 1 ? (void*)Kb : (void*)Vt;
  gemm_core(A, Bt, C, z == 2 ? 1 : 0);
}

__global__ __launch_bounds__(256) void k_gemm_o(const __hip_bfloat16* __restrict__ CTX,
                                                const __hip_bfloat16* __restrict__ Wot,
                                                float* __restrict__ Out) {
  gemm_core(CTX, Wot, Out, 2);
}

// ---------------- skewed rel bias, block-local skew + coalesced stores --------------
// One block per lower-tri 64x64 output tile u = ti*(ti+1)/2 + tj (tj<=ti).
// qe strip: rows i' in [0,64), cols l in [l0, l0+128), l0 = 960 - 64*(ti-tj).
// Output: SREL tile in flash fragment order; S_rel[i'][j'] = qe[i'][63 + j' - i'].
__global__ __launch_bounds__(256) void k_srel(const __hip_bfloat16* __restrict__ Qb,
                                              const __hip_bfloat16* __restrict__ relT,
                                              __hip_bfloat16* __restrict__ SREL) {
  __shared__ __hip_bfloat16 Qs[64 * 64];
  __shared__ __hip_bfloat16 Rs[128 * 64];
  __shared__ __hip_bfloat16 Cs[64 * 136];  // qe strip, padded stride
  const int bh = blockIdx.y, h = bh & 7;
  const int u = blockIdx.x;
  int ti = (int)((__builtin_sqrtf(8.0f * u + 1.0f) - 1.0f) * 0.5f);
  while ((ti + 1) * (ti + 2) / 2 <= u) ++ti;
  while (ti * (ti + 1) / 2 > u) --ti;
  const int tj = u - ti * (ti + 1) / 2;
  const int l0 = 960 - 64 * (ti - tj);

  const int t = threadIdx.x, w = t >> 6, lane = t & 63;
  const int quad = lane >> 4, l16 = lane & 15;
  const __hip_bfloat16* Qp = Qb + ((size_t)bh * SS + ti * 64) * SDH;
  const __hip_bfloat16* Rp = relT + (size_t)h * SS * SDH;

  // stage Q tile (64x64, 2 chunks) and relT strip (128x64, 4 chunks), XOR-swizzled
#pragma unroll
  for (int c = 0; c < 2; ++c) {
    int ofs = c * 256 + t;
    int row = ofs >> 3, col = (ofs & 7) ^ (row & 7);
    load_lds16(Qp + (size_t)row * SDH + col * 8,
               (char*)Qs + (size_t)(c * 256 + w * 64) * 16);
  }
#pragma unroll
  for (int c = 0; c < 4; ++c) {
    int ofs = c * 256 + t;
    int row = ofs >> 3, col = (ofs & 7) ^ (row & 7);
    int lr = l0 + row;
    if (lr > 1023) lr = 1023;  // clamp: OOB rows feed only causally-masked outputs
    load_lds16(Rp + (size_t)lr * SDH + col * 8,
               (char*)Rs + (size_t)(c * 256 + w * 64) * 16);
  }
  __syncthreads();

  // each wave: 16 i-rows x 128 l-cols
  f32x4 zero4 = {0.0f, 0.0f, 0.0f, 0.0f};
  f32x4 acc[8];
#pragma unroll
  for (int nj = 0; nj < 8; ++nj) acc[nj] = zero4;
  bf16x8 af[2];
  {
    int row = w * 16 + l16;
#pragma unroll
    for (int ks = 0; ks < 2; ++ks)
      af[ks] = *(const bf16x8*)((const char*)Qs + row * 128 +
                                ((ks * 4 + quad) ^ (row & 7)) * 16);
  }
#pragma unroll
  for (int nj = 0; nj < 8; ++nj) {
    int row = nj * 16 + l16;
    bf16x8 b0 = *(const bf16x8*)((const char*)Rs + row * 128 + ((quad) ^ (row & 7)) * 16);
    bf16x8 b1 = *(const bf16x8*)((const char*)Rs + row * 128 + ((4 + quad) ^ (row & 7)) * 16);
    acc[nj] = MFMA(af[0], b0, acc[nj]);
    acc[nj] = MFMA(af[1], b1, acc[nj]);
  }
  // C-layout -> Cs[i'][l'] bf16
#pragma unroll
  for (int nj = 0; nj < 8; ++nj)
#pragma unroll
    for (int r = 0; r < 4; ++r)
      Cs[(w * 16 + quad * 4 + r) * 136 + nj * 16 + l16] = __float2bfloat16(acc[nj][r]);
  __syncthreads();

  // skew-extract + fully-coalesced store: thread t writes elements [16t, 16t+16)
  bf16x8 o0, o1;
#pragma unroll
  for (int rr = 0; rr < 16; ++rr) {
    int col = (rr >> 2) * 16 + (t & 15);
    int row = (t >> 6) * 16 + ((t >> 4) & 3) * 4 + (rr & 3);
    int lp = 63 + col - row;  // in [0,126]
    short v = *(const short*)&Cs[row * 136 + lp];
    if (rr < 8) o0[rr] = v; else o1[rr - 8] = v;
  }
  __hip_bfloat16* dst = SREL + ((size_t)bh * 136 + u) * 4096 + t * 16;
  *(bf16x8*)dst = o0;
  *(bf16x8*)(dst + 8) = o1;
}

// ---------------- split-j flash: static-shift softmax, partial (O,l) ----------------
__device__ const int TTm[40] = {0,1,2,3,4,4,5,5,6,6,7,7,8,8,8,9,9,9,10,10,10,11,11,11,
                                12,12,12,12,13,13,13,13,14,14,14,14,15,15,15,15};
__device__ const int CCm[40] = {0,0,0,0,0,1,0,1,0,1,0,1,0,1,2,0,1,2,0,1,2,0,1,2,
                                0,1,2,3,0,1,2,3,0,1,2,3,0,1,2,3};

__global__ __launch_bounds__(256) void k_flash(const __hip_bfloat16* __restrict__ Qb,
                                               const __hip_bfloat16* __restrict__ Kb,
                                               const __hip_bfloat16* __restrict__ Vt,
                                               const __hip_bfloat16* __restrict__ SREL,
                                               float* __restrict__ Opart,
                                               float* __restrict__ lpart) {
  __shared__ __hip_bfloat16 Klds[64 * 64];
  __shared__ __hip_bfloat16 Vlds[64 * 64];
  __shared__ __hip_bfloat16 Pbuf[64 * 72];
  const int t = threadIdx.x, w = t >> 6, lane = t & 63;
  const int quad = lane >> 4, l16 = lane & 15;
  const int idx = blockIdx.x, bh = blockIdx.y;
  const int tI = TTm[idx], c = CCm[idx];
  const int i0 = tI * 64;
  const int rem = tI + 1 - c * 4;
  const int nt = rem < 4 ? rem : 4;
  const size_t qbase = (size_t)bh * SS * SDH;

  const int qrow = i0 + w * 16 + l16;
  bf16x8 qf0 = *(const bf16x8*)(Qb + qbase + (size_t)qrow * SDH + quad * 8);
  bf16x8 qf1 = *(const bf16x8*)(Qb + qbase + (size_t)qrow * SDH + 32 + quad * 8);

  f32x4 zero4 = {0.0f, 0.0f, 0.0f, 0.0f};
  f32x4 acc_o[4];
#pragma unroll
  for (int dt = 0; dt < 4; ++dt) acc_o[dt] = zero4;
  float ls[4] = {0.0f, 0.0f, 0.0f, 0.0f};
  const int irow_base = i0 + w * 16 + quad * 4;
  const size_t sbase = ((size_t)bh * 136 + ((tI * (tI + 1)) >> 1)) * 4096 +
                       (size_t)(w * 64 + lane) * 16;

  for (int jt = 0; jt < nt; ++jt) {
    const int jtile = c * 4 + jt, j0 = jtile * 64;
#pragma unroll
    for (int cc = 0; cc < 2; ++cc) {
      int ofs = cc * 256 + t;
      int row = ofs >> 3, col = (ofs & 7) ^ (row & 7);
      load_lds16(Kb + qbase + (size_t)(j0 + row) * SDH + col * 8,
                 (char*)Klds + (size_t)(cc * 256 + w * 64) * 16);
      load_lds16(Vt + (size_t)bh * SDH * SS + (size_t)row * SS + j0 + col * 8,
                 (char*)Vlds + (size_t)(cc * 256 + w * 64) * 16);
    }
    const __hip_bfloat16* sp = SREL + sbase + (size_t)jtile * 4096;
    bf16x8 sv0 = *(const bf16x8*)(sp);
    bf16x8 sv1 = *(const bf16x8*)(sp + 8);
    __syncthreads();

    f32x4 s[4];
#pragma unroll
    for (int nj = 0; nj < 4; ++nj) {
      int row = nj * 16 + l16;
      bf16x8 b0 = *(const bf16x8*)((const char*)Klds + row * 128 + (quad ^ (row & 7)) * 16);
      bf16x8 b1 = *(const bf16x8*)((const char*)Klds + row * 128 + ((4 + quad) ^ (row & 7)) * 16);
      f32x4 z = zero4;
      z = MFMA(qf0, b0, z);
      z = MFMA(qf1, b1, z);
      s[nj] = z;
    }
#pragma unroll
    for (int nj = 0; nj < 4; ++nj) {
      int jcol = j0 + nj * 16 + l16;
#pragma unroll
      for (int r = 0; r < 4; ++r) {
        int irow = irow_base + r;
        short sb = (nj < 2) ? sv0[(nj & 1) * 4 + r] : sv1[(nj & 1) * 4 + r];
        float val = (s[nj][r] + bf16bits(sb)) * 0.125f - 8.0f;
        float p = (jcol <= irow) ? __expf(val) : 0.0f;
        s[nj][r] = p;
        ls[r] += p;
      }
    }
#pragma unroll
    for (int nj = 0; nj < 4; ++nj)
#pragma unroll
      for (int r = 0; r < 4; ++r)
        Pbuf[(w * 16 + quad * 4 + r) * 72 + nj * 16 + l16] = __float2bfloat16(s[nj][r]);
    __syncthreads();
#pragma unroll
    for (int js = 0; js < 2; ++js) {
      bf16x8 pa = *(const bf16x8*)(Pbuf + (size_t)(w * 16 + l16) * 72 + js * 32 + quad * 8);
#pragma unroll
      for (int dt = 0; dt < 4; ++dt) {
        int row = dt * 16 + l16;
        bf16x8 vb = *(const bf16x8*)((const char*)Vlds + row * 128 +
                                     ((js * 4 + quad) ^ (row & 7)) * 16);
        acc_o[dt] = MFMA(pa, vb, acc_o[dt]);
      }
    }
    __syncthreads();
  }
  const size_t pbase = (size_t)(bh * 16 + tI) * 4 + c;
  float* Op = Opart + pbase * 4096;
#pragma unroll
  for (int r = 0; r < 4; ++r) {
    float sum = ls[r];
    sum += __shfl_xor(sum, 1, 64);
    sum += __shfl_xor(sum, 2, 64);
    sum += __shfl_xor(sum, 4, 64);
    sum += __shfl_xor(sum, 8, 64);
    int row = w * 16 + quad * 4 + r;
#pragma unroll
    for (int dt = 0; dt < 4; ++dt) Op[row * 64 + dt * 16 + l16] = acc_o[dt][r];
    if (l16 == 0) lpart[pbase * 64 + row] = sum;
  }
}

// ---------------- combine partials, normalize, write CTX bf16 ----------------
__global__ __launch_bounds__(256) void k_reduce(const float* __restrict__ Opart,
                                                const float* __restrict__ lpart,
                                                __hip_bfloat16* __restrict__ CTX) {
  const int tI = blockIdx.x, bh = blockIdx.y, b = bh >> 3, h = bh & 7;
  const int nc = tI / 4 + 1;
  const int tid = threadIdx.x;
  __shared__ float lsum[64];
  const size_t base = (size_t)(bh * 16 + tI) * 4;
  if (tid < 64) {
    float s = 0.0f;
    for (int cc = 0; cc < nc; ++cc) s += lpart[(base + cc) * 64 + tid];
    lsum[tid] = s;
  }
  __syncthreads();
  const int e0 = tid * 16;
  const int row = e0 >> 6, d0 = e0 & 63;
  float4 o[4] = {};
  for (int cc = 0; cc < nc; ++cc) {
    const float4* p = (const float4*)(Opart + (base + cc) * 4096);
#pragma unroll
    for (int vv = 0; vv < 4; ++vv) {
      float4 x = p[tid * 4 + vv];
      o[vv].x += x.x; o[vv].y += x.y; o[vv].z += x.z; o[vv].w += x.w;
    }
  }
  const float rl = 1.0f / lsum[row];
  __hip_bfloat16* op = CTX + ((size_t)b * SS + tI * 64 + row) * SD + h * SDH + d0;
#pragma unroll
  for (int vv = 0; vv < 4; ++vv) {
    op[vv * 4 + 0] = __float2bfloat16(o[vv].x * rl);
    op[vv * 4 + 1] = __float2bfloat16(o[vv].y * rl);
    op[vv * 4 + 2] = __float2bfloat16(o[vv].z * rl);
    op[vv * 4 + 3] = __float2bfloat16(o[vv].w * rl);
  }
}

extern "C" void kernel_launch(void* const* d_in, const int* in_sizes, int n_in,
                              void* d_out, int out_size, void* d_ws, size_t ws_size,
                              hipStream_t stream) {
  const float* queries = (const float*)d_in[0];
  const float* keys    = (const float*)d_in[1];
  const float* values  = (const float*)d_in[2];
  const float* Wq = (const float*)d_in[4];
  const float* Wk = (const float*)d_in[5];
  const float* Wv = (const float*)d_in[6];
  const float* Wo = (const float*)d_in[7];
  const float* rel = (const float*)d_in[8];

  char* ws = (char*)d_ws;
  size_t off = 0;
  auto alloc = [&](size_t bytes) {
    char* p = ws + off;
    off += (bytes + 255) & ~(size_t)255;
    return p;
  };
  const size_t XB = (size_t)SB * SS * SD * 2;   // 4 MiB
  const size_t WB = (size_t)SD * SD * 2;        // 512 KiB
  __hip_bfloat16* Wqt  = (__hip_bfloat16*)alloc(WB);
  __hip_bfloat16* Wkt  = (__hip_bfloat16*)alloc(WB);
  __hip_bfloat16* Wvt  = (__hip_bfloat16*)alloc(WB);
  __hip_bfloat16* Wot  = (__hip_bfloat16*)alloc(WB);
  __hip_bfloat16* relT = (__hip_bfloat16*)alloc((size_t)SH * SS * SDH * 2);
  __hip_bfloat16* Qb   = (__hip_bfloat16*)alloc(XB);
  __hip_bfloat16* Kb   = (__hip_bfloat16*)alloc(XB);
  __hip_bfloat16* Vt   = (__hip_bfloat16*)alloc(XB);
  __hip_bfloat16* CTX  = (__hip_bfloat16*)alloc(XB);
  char* uni = alloc((size_t)2048 * 4096 * 4 + (size_t)2048 * 64 * 4);  // 32.5 MiB
  __hip_bfloat16* Xq = (__hip_bfloat16*)uni;
  __hip_bfloat16* Xk = (__hip_bfloat16*)(uni + XB);
  __hip_bfloat16* Xv = (__hip_bfloat16*)(uni + 2 * XB);
  float* Opart = (float*)uni;
  float* lpart = (float*)(uni + (size_t)2048 * 4096 * 4);
  __hip_bfloat16* SREL = (__hip_bfloat16*)alloc((size_t)SB * SH * 136 * 4096 * 2);
  if (off > ws_size) return;

  const int n2 = SB * SS * SD / 2;
  k_cvt3<<<dim3(512, 3), dim3(256), 0, stream>>>((const float2*)queries, (const float2*)keys,
                                                 (const float2*)values, (__hip_bfloat162*)Xq,
                                                 (__hip_bfloat162*)Xk, (__hip_bfloat162*)Xv, n2);
  k_trw<<<dim3(16, 16, 4), dim3(256), 0, stream>>>(Wq, Wk, Wv, Wo, Wqt, Wkt, Wvt, Wot);
  k_trr<<<dim3(SS / 32, SDH / 32, SH), dim3(256), 0, stream>>>(rel, relT);

  k_gemm_qkv<<<dim3(SD / 64, SB * SS / 128, 3), dim3(256), 0, stream>>>(
      Xq, Xk, Xv, Wqt, Wkt, Wvt, Qb, Kb, Vt);
  k_srel<<<dim3(136, SB * SH), dim3(256), 0, stream>>>(Qb, relT, SREL);
  k_flash<<<dim3(40, SB * SH), dim3(256), 0, stream>>>(Qb, Kb, Vt, SREL, Opart, lpart);
  k_reduce<<<dim3(16, SB * SH), dim3(256), 0, stream>>>(Opart, lpart, CTX);
  k_gemm_o<<<dim3(SD / 64, SB * SS / 128), dim3(256), 0, stream>>>(CTX, Wot, (float*)d_out);
}

// Round 4
// 158.742 us; speedup vs baseline: 1.5132x; 1.0613x over previous
//
#include <hip/hip_runtime.h>
#include <hip/hip_bf16.h>

// Problem constants: B=4, S=1024, D=512, H=8, DH=64, L=S=1024
#define SB 4
#define SS 1024
#define SD 512
#define SH 8
#define SDH 64

typedef short bf16x8 __attribute__((ext_vector_type(8)));   // 8 bf16 in 4 VGPRs
typedef float f32x4 __attribute__((ext_vector_type(4)));

#define MFMA(a, b, c) __builtin_amdgcn_mfma_f32_16x16x32_bf16(a, b, c, 0, 0, 0)

__device__ __forceinline__ void load_lds16(const void* g, void* l) {
  __builtin_amdgcn_global_load_lds(
      (__attribute__((address_space(1))) void*)(const_cast<void*>(g)),
      (__attribute__((address_space(3))) void*)(l), 16, 0, 0);
}

// ---------------- fused prep: fp32->bf16 converts + weight/rel transposes -----------
// blockIdx.y: 0..2 = cvt q/k/v (x strided); 3 = transpose Wq/Wk; 4 = Wv/Wo; 5 = rel_emb
__global__ __launch_bounds__(256) void k_prep(
    const float* __restrict__ q, const float* __restrict__ k, const float* __restrict__ v,
    const float* __restrict__ Wq, const float* __restrict__ Wk, const float* __restrict__ Wv,
    const float* __restrict__ Wo, const float* __restrict__ rel,
    __hip_bfloat16* __restrict__ Xq, __hip_bfloat16* __restrict__ Xk,
    __hip_bfloat16* __restrict__ Xv, __hip_bfloat16* __restrict__ Wqt,
    __hip_bfloat16* __restrict__ Wkt, __hip_bfloat16* __restrict__ Wvt,
    __hip_bfloat16* __restrict__ Wot, __hip_bfloat16* __restrict__ relT) {
  __shared__ float tile[32][33];
  const int y = blockIdx.y, x = blockIdx.x, t = threadIdx.x;
  if (y < 3) {
    const float2* in = (const float2*)(y == 0 ? q : y == 1 ? k : v);
    __hip_bfloat162* out = (__hip_bfloat162*)(y == 0 ? Xq : y == 1 ? Xk : Xv);
    const int n2 = SB * SS * SD / 2;
    int i = x * 256 + t, st = 512 * 256;
    for (; i < n2; i += st) out[i] = __float22bfloat162_rn(in[i]);
    return;
  }
  int tx = t & 31, ty = t >> 5;
  if (y < 5) {
    int which = (y - 3) * 2 + (x >> 8), idx = x & 255;
    const float* ip = which == 0 ? Wq : which == 1 ? Wk : which == 2 ? Wv : Wo;
    __hip_bfloat16* op = which == 0 ? Wqt : which == 1 ? Wkt : which == 2 ? Wvt : Wot;
    int c0 = (idx & 15) * 32, r0 = (idx >> 4) * 32;
    for (int rr = ty; rr < 32; rr += 8) tile[rr][tx] = ip[(size_t)(r0 + rr) * SD + c0 + tx];
    __syncthreads();
    for (int cc = ty; cc < 32; cc += 8)
      op[(size_t)(c0 + cc) * SD + r0 + tx] = __float2bfloat16(tile[tx][cc]);
    return;
  }
  // rel_emb [H, DH=64, L=1024] -> relT [H, L, DH]
  int hd = x >> 6, idx = x & 63;
  int c0 = (idx >> 1) * 32, r0 = (idx & 1) * 32;
  const float* ip = rel + (size_t)hd * SDH * SS;
  __hip_bfloat16* op = relT + (size_t)hd * SDH * SS;
  for (int rr = ty; rr < 32; rr += 8) tile[rr][tx] = ip[(size_t)(r0 + rr) * SS + c0 + tx];
  __syncthreads();
  for (int cc = ty; cc < 32; cc += 8)
    op[(size_t)(c0 + cc) * SDH + r0 + tx] = __float2bfloat16(tile[tx][cc]);
}

// ---------------- GEMM core: C[4096,512] = A[4096,512] * Bt[512,512]^T, 128x64 tile ----
__device__ __forceinline__ void gemm_core(const __hip_bfloat16* __restrict__ A,
                                          const __hip_bfloat16* __restrict__ Bt,
                                          void* __restrict__ Cout, int mode) {
  __shared__ __hip_bfloat16 As[128 * 64];
  __shared__ __hip_bfloat16 Bs[64 * 64];
  const int t = threadIdx.x, w = t >> 6, lane = t & 63;
  const int quad = lane >> 4, l16 = lane & 15;
  const int m0 = blockIdx.y * 128, n0 = blockIdx.x * 64;
  const int wm = (w >> 1) * 64, wn = (w & 1) * 32;
  f32x4 zero4 = {0.0f, 0.0f, 0.0f, 0.0f};
  f32x4 acc[4][2];
#pragma unroll
  for (int mi = 0; mi < 4; ++mi)
#pragma unroll
    for (int nj = 0; nj < 2; ++nj) acc[mi][nj] = zero4;

  for (int kt = 0; kt < SD; kt += 64) {
#pragma unroll
    for (int c = 0; c < 4; ++c) {
      int ofs = c * 256 + t;
      int row = ofs >> 3, col = (ofs & 7) ^ (row & 7);
      load_lds16(A + (size_t)(m0 + row) * SD + kt + col * 8,
                 (char*)As + (size_t)(c * 256 + w * 64) * 16);
    }
#pragma unroll
    for (int c = 0; c < 2; ++c) {
      int ofs = c * 256 + t;
      int row = ofs >> 3, col = (ofs & 7) ^ (row & 7);
      load_lds16(Bt + (size_t)(n0 + row) * SD + kt + col * 8,
                 (char*)Bs + (size_t)(c * 256 + w * 64) * 16);
    }
    __syncthreads();
    bf16x8 af[4][2], bfr[2][2];
#pragma unroll
    for (int mi = 0; mi < 4; ++mi) {
      int row = wm + mi * 16 + l16;
#pragma unroll
      for (int ks = 0; ks < 2; ++ks)
        af[mi][ks] = *(const bf16x8*)((const char*)As + row * 128 +
                                      ((ks * 4 + quad) ^ (row & 7)) * 16);
    }
#pragma unroll
    for (int nj = 0; nj < 2; ++nj) {
      int row = wn + nj * 16 + l16;
#pragma unroll
      for (int ks = 0; ks < 2; ++ks)
        bfr[nj][ks] = *(const bf16x8*)((const char*)Bs + row * 128 +
                                       ((ks * 4 + quad) ^ (row & 7)) * 16);
    }
#pragma unroll
    for (int mi = 0; mi < 4; ++mi)
#pragma unroll
      for (int nj = 0; nj < 2; ++nj) {
        acc[mi][nj] = MFMA(af[mi][0], bfr[nj][0], acc[mi][nj]);
        acc[mi][nj] = MFMA(af[mi][1], bfr[nj][1], acc[mi][nj]);
      }
    __syncthreads();
  }
#pragma unroll
  for (int mi = 0; mi < 4; ++mi)
#pragma unroll
    for (int nj = 0; nj < 2; ++nj)
#pragma unroll
      for (int r = 0; r < 4; ++r) {
        int m = m0 + wm + mi * 16 + quad * 4 + r;
        int n = n0 + wn + nj * 16 + l16;
        float v = acc[mi][nj][r];
        if (mode == 2) {
          ((float*)Cout)[(size_t)m * SD + n] = v;
        } else {
          int b = m >> 10, s = m & 1023, hh = n >> 6, dh = n & 63;
          __hip_bfloat16 bv = __float2bfloat16(v);
          if (mode == 0)
            ((__hip_bfloat16*)Cout)[((size_t)(b * SH + hh) * SS + s) * SDH + dh] = bv;
          else
            ((__hip_bfloat16*)Cout)[((size_t)(b * SH + hh) * SDH + dh) * SS + s] = bv;
        }
      }
}

__global__ __launch_bounds__(256) void k_gemm_qkv(
    const __hip_bfloat16* __restrict__ Xq, const __hip_bfloat16* __restrict__ Xk,
    const __hip_bfloat16* __restrict__ Xv, const __hip_bfloat16* __restrict__ Wqt,
    const __hip_bfloat16* __restrict__ Wkt, const __hip_bfloat16* __restrict__ Wvt,
    __hip_bfloat16* __restrict__ Qb, __hip_bfloat16* __restrict__ Kb,
    __hip_bfloat16* __restrict__ Vt) {
  int z = blockIdx.z;
  const __hip_bfloat16* A = z == 0 ? Xq : z == 1 ? Xk : Xv;
  const __hip_bfloat16* Bt = z == 0 ? Wqt : z == 1 ? Wkt : Wvt;
  void* C = z == 0 ? (void*)Qb : z == 1 ? (void*)Kb : (void*)Vt;
  gemm_core(A, Bt, C, z == 2 ? 1 : 0);
}

__global__ __launch_bounds__(256) void k_gemm_o(const __hip_bfloat16* __restrict__ CTX,
                                                const __hip_bfloat16* __restrict__ Wot,
                                                float* __restrict__ Out) {
  gemm_core(CTX, Wot, Out, 2);
}

// ---------------- split-j flash with fused rel-bias (QE computed in-kernel) ----------
// Bias identity: bias[i'][j'] = qe[i', l], l-l0 = 63 + j' - i', l0 = 960-64*(tI-jtile).
// QE reuses the Q A-fragments already in registers; its C-layout rows are wave-private,
// so the QE-strip LDS buffer also hosts P (cols 0..63) for the PV A-operand reload.
__device__ const int TTm[40] = {0,1,2,3,4,4,5,5,6,6,7,7,8,8,8,9,9,9,10,10,10,11,11,11,
                                12,12,12,12,13,13,13,13,14,14,14,14,15,15,15,15};
__device__ const int CCm[40] = {0,0,0,0,0,1,0,1,0,1,0,1,0,1,2,0,1,2,0,1,2,0,1,2,
                                0,1,2,3,0,1,2,3,0,1,2,3,0,1,2,3};

__global__ __launch_bounds__(256) void k_flash(const __hip_bfloat16* __restrict__ Qb,
                                               const __hip_bfloat16* __restrict__ Kb,
                                               const __hip_bfloat16* __restrict__ Vt,
                                               const __hip_bfloat16* __restrict__ relT,
                                               float* __restrict__ Opart,
                                               float* __restrict__ lpart) {
  __shared__ __hip_bfloat16 Klds[64 * 64];    // 8 KiB
  __shared__ __hip_bfloat16 Vlds[64 * 64];    // 8 KiB
  __shared__ __hip_bfloat16 REs[128 * 64];    // 16 KiB, rel strip
  __shared__ __hip_bfloat16 QEP[64 * 136];    // 17 KiB, QE strip + aliased P
  const int t = threadIdx.x, w = t >> 6, lane = t & 63;
  const int quad = lane >> 4, l16 = lane & 15;
  const int idx = blockIdx.x, bh = blockIdx.y, h = bh & 7;
  const int tI = TTm[idx], c = CCm[idx];
  const int i0 = tI * 64;
  const int rem = tI + 1 - c * 4;
  const int nt = rem < 4 ? rem : 4;
  const size_t qbase = (size_t)bh * SS * SDH;
  const __hip_bfloat16* Rp = relT + (size_t)h * SS * SDH;

  const int qrow = i0 + w * 16 + l16;
  bf16x8 qf0 = *(const bf16x8*)(Qb + qbase + (size_t)qrow * SDH + quad * 8);
  bf16x8 qf1 = *(const bf16x8*)(Qb + qbase + (size_t)qrow * SDH + 32 + quad * 8);

  f32x4 zero4 = {0.0f, 0.0f, 0.0f, 0.0f};
  f32x4 acc_o[4];
#pragma unroll
  for (int dt = 0; dt < 4; ++dt) acc_o[dt] = zero4;
  float ls[4] = {0.0f, 0.0f, 0.0f, 0.0f};
  const int rloc = quad * 4;  // local C-layout row base within the wave's 16 rows
  const int irow_base = i0 + w * 16 + rloc;

  for (int jt = 0; jt < nt; ++jt) {
    const int jtile = c * 4 + jt, j0 = jtile * 64;
    const int l0 = 960 - 64 * (tI - jtile);
    // stage K tile, V tile (2 chunks each) + rel strip rows [l0, l0+128) (4 chunks)
#pragma unroll
    for (int cc = 0; cc < 2; ++cc) {
      int ofs = cc * 256 + t;
      int row = ofs >> 3, col = (ofs & 7) ^ (row & 7);
      load_lds16(Kb + qbase + (size_t)(j0 + row) * SDH + col * 8,
                 (char*)Klds + (size_t)(cc * 256 + w * 64) * 16);
      load_lds16(Vt + (size_t)bh * SDH * SS + (size_t)row * SS + j0 + col * 8,
                 (char*)Vlds + (size_t)(cc * 256 + w * 64) * 16);
    }
#pragma unroll
    for (int cc = 0; cc < 4; ++cc) {
      int ofs = cc * 256 + t;
      int row = ofs >> 3, col = (ofs & 7) ^ (row & 7);
      int lr = l0 + row;
      if (lr > 1023) lr = 1023;  // OOB rows feed only causally-masked bias entries
      load_lds16(Rp + (size_t)lr * SDH + col * 8,
                 (char*)REs + (size_t)(cc * 256 + w * 64) * 16);
    }
    __syncthreads();

    // S = Q K^T
    f32x4 s[4];
#pragma unroll
    for (int nj = 0; nj < 4; ++nj) {
      int row = nj * 16 + l16;
      bf16x8 b0 = *(const bf16x8*)((const char*)Klds + row * 128 + (quad ^ (row & 7)) * 16);
      bf16x8 b1 = *(const bf16x8*)((const char*)Klds + row * 128 + ((4 + quad) ^ (row & 7)) * 16);
      f32x4 z = zero4;
      z = MFMA(qf0, b0, z);
      z = MFMA(qf1, b1, z);
      s[nj] = z;
    }
    // QE strip: 16 rows x 128 l-cols per wave, same A-fragments
#pragma unroll
    for (int nc = 0; nc < 8; ++nc) {
      int row = nc * 16 + l16;
      bf16x8 b0 = *(const bf16x8*)((const char*)REs + row * 128 + (quad ^ (row & 7)) * 16);
      bf16x8 b1 = *(const bf16x8*)((const char*)REs + row * 128 + ((4 + quad) ^ (row & 7)) * 16);
      f32x4 e = zero4;
      e = MFMA(qf0, b0, e);
      e = MFMA(qf1, b1, e);
#pragma unroll
      for (int r = 0; r < 4; ++r)
        QEP[(w * 16 + rloc + r) * 136 + nc * 16 + l16] = __float2bfloat16(e[r]);
    }
    __syncthreads();

    // bias from QEP (wave-private rows), softmax with static shift
#pragma unroll
    for (int nj = 0; nj < 4; ++nj) {
      int jc = nj * 16 + l16, jcol = j0 + jc;
#pragma unroll
      for (int r = 0; r < 4; ++r) {
        int il = w * 16 + rloc + r;           // local row
        int irow = i0 + il;
        float bias = __bfloat162float(QEP[il * 136 + 63 + jc - (rloc + r)]);
        float val = (s[nj][r] + bias) * 0.125f - 8.0f;
        float p = (jcol <= irow) ? __expf(val) : 0.0f;
        s[nj][r] = p;
        ls[r] += p;
      }
    }
    // P into QEP cols 0..63 (same wave-private rows)
#pragma unroll
    for (int nj = 0; nj < 4; ++nj)
#pragma unroll
      for (int r = 0; r < 4; ++r)
        QEP[(w * 16 + rloc + r) * 136 + nj * 16 + l16] = __float2bfloat16(s[nj][r]);
    __syncthreads();

    // O += P V
#pragma unroll
    for (int js = 0; js < 2; ++js) {
      bf16x8 pa = *(const bf16x8*)(QEP + (size_t)(w * 16 + l16) * 136 + js * 32 + quad * 8);
#pragma unroll
      for (int dt = 0; dt < 4; ++dt) {
        int row = dt * 16 + l16;
        bf16x8 vb = *(const bf16x8*)((const char*)Vlds + row * 128 +
                                     ((js * 4 + quad) ^ (row & 7)) * 16);
        acc_o[dt] = MFMA(pa, vb, acc_o[dt]);
      }
    }
    __syncthreads();
  }
  // epilogue: reduce row sums across the 16-lane group, write partial O and l
  const size_t pbase = (size_t)(bh * 16 + tI) * 4 + c;
  float* Op = Opart + pbase * 4096;
#pragma unroll
  for (int r = 0; r < 4; ++r) {
    float sum = ls[r];
    sum += __shfl_xor(sum, 1, 64);
    sum += __shfl_xor(sum, 2, 64);
    sum += __shfl_xor(sum, 4, 64);
    sum += __shfl_xor(sum, 8, 64);
    int row = w * 16 + rloc + r;
#pragma unroll
    for (int dt = 0; dt < 4; ++dt) Op[row * 64 + dt * 16 + l16] = acc_o[dt][r];
    if (l16 == 0) lpart[pbase * 64 + row] = sum;
  }
}

// ---------------- combine partials, normalize, write CTX bf16 ----------------
__global__ __launch_bounds__(256) void k_reduce(const float* __restrict__ Opart,
                                                const float* __restrict__ lpart,
                                                __hip_bfloat16* __restrict__ CTX) {
  const int tI = blockIdx.x, bh = blockIdx.y, b = bh >> 3, h = bh & 7;
  const int nc = tI / 4 + 1;
  const int tid = threadIdx.x;
  __shared__ float lsum[64];
  const size_t base = (size_t)(bh * 16 + tI) * 4;
  if (tid < 64) {
    float s = 0.0f;
    for (int cc = 0; cc < nc; ++cc) s += lpart[(base + cc) * 64 + tid];
    lsum[tid] = s;
  }
  __syncthreads();
  const int e0 = tid * 16;
  const int row = e0 >> 6, d0 = e0 & 63;
  float4 o[4] = {};
  for (int cc = 0; cc < nc; ++cc) {
    const float4* p = (const float4*)(Opart + (base + cc) * 4096);
#pragma unroll
    for (int vv = 0; vv < 4; ++vv) {
      float4 x = p[tid * 4 + vv];
      o[vv].x += x.x; o[vv].y += x.y; o[vv].z += x.z; o[vv].w += x.w;
    }
  }
  const float rl = 1.0f / lsum[row];
  __hip_bfloat16* op = CTX + ((size_t)b * SS + tI * 64 + row) * SD + h * SDH + d0;
#pragma unroll
  for (int vv = 0; vv < 4; ++vv) {
    op[vv * 4 + 0] = __float2bfloat16(o[vv].x * rl);
    op[vv * 4 + 1] = __float2bfloat16(o[vv].y * rl);
    op[vv * 4 + 2] = __float2bfloat16(o[vv].z * rl);
    op[vv * 4 + 3] = __float2bfloat16(o[vv].w * rl);
  }
}

extern "C" void kernel_launch(void* const* d_in, const int* in_sizes, int n_in,
                              void* d_out, int out_size, void* d_ws, size_t ws_size,
                              hipStream_t stream) {
  const float* queries = (const float*)d_in[0];
  const float* keys    = (const float*)d_in[1];
  const float* values  = (const float*)d_in[2];
  const float* Wq = (const float*)d_in[4];
  const float* Wk = (const float*)d_in[5];
  const float* Wv = (const float*)d_in[6];
  const float* Wo = (const float*)d_in[7];
  const float* rel = (const float*)d_in[8];

  char* ws = (char*)d_ws;
  size_t off = 0;
  auto alloc = [&](size_t bytes) {
    char* p = ws + off;
    off += (bytes + 255) & ~(size_t)255;
    return p;
  };
  const size_t XB = (size_t)SB * SS * SD * 2;   // 4 MiB
  const size_t WB = (size_t)SD * SD * 2;        // 512 KiB
  __hip_bfloat16* Wqt  = (__hip_bfloat16*)alloc(WB);
  __hip_bfloat16* Wkt  = (__hip_bfloat16*)alloc(WB);
  __hip_bfloat16* Wvt  = (__hip_bfloat16*)alloc(WB);
  __hip_bfloat16* Wot  = (__hip_bfloat16*)alloc(WB);
  __hip_bfloat16* relT = (__hip_bfloat16*)alloc((size_t)SH * SS * SDH * 2);
  __hip_bfloat16* Qb   = (__hip_bfloat16*)alloc(XB);
  __hip_bfloat16* Kb   = (__hip_bfloat16*)alloc(XB);
  __hip_bfloat16* Vt   = (__hip_bfloat16*)alloc(XB);
  __hip_bfloat16* CTX  = (__hip_bfloat16*)alloc(XB);
  // union region: Xq/Xk/Xv (12 MiB, dead after qkv gemm) aliased by Opart/lpart
  char* uni = alloc((size_t)2048 * 4096 * 4 + (size_t)2048 * 64 * 4);  // 32.5 MiB
  __hip_bfloat16* Xq = (__hip_bfloat16*)uni;
  __hip_bfloat16* Xk = (__hip_bfloat16*)(uni + XB);
  __hip_bfloat16* Xv = (__hip_bfloat16*)(uni + 2 * XB);
  float* Opart = (float*)uni;
  float* lpart = (float*)(uni + (size_t)2048 * 4096 * 4);
  if (off > ws_size) return;

  k_prep<<<dim3(512, 6), dim3(256), 0, stream>>>(
      queries, keys, values, Wq, Wk, Wv, Wo, rel,
      Xq, Xk, Xv, Wqt, Wkt, Wvt, Wot, relT);
  k_gemm_qkv<<<dim3(SD / 64, SB * SS / 128, 3), dim3(256), 0, stream>>>(
      Xq, Xk, Xv, Wqt, Wkt, Wvt, Qb, Kb, Vt);
  k_flash<<<dim3(40, SB * SH), dim3(256), 0, stream>>>(Qb, Kb, Vt, relT, Opart, lpart);
  k_reduce<<<dim3(16, SB * SH), dim3(256), 0, stream>>>(Opart, lpart, CTX);
  k_gemm_o<<<dim3(SD / 64, SB * SS / 128), dim3(256), 0, stream>>>(CTX, Wot, (float*)d_out);
}